// Round 2
// baseline (319.803 us; speedup 1.0000x reference)
//
#include <hip/hip_runtime.h>
#include <math.h>

#define TN 4096
#define HN 2048
#define NB 32
#define NCH 9
#define NCODES 512
#define CDIM 64

__device__ __forceinline__ float2 cmulf(float2 a, float2 b) {
    return make_float2(a.x * b.x - a.y * b.y, a.x * b.y + a.y * b.x);
}

__global__ __launch_bounds__(256) void zero_kernel(float* __restrict__ p, int n) {
    int i = blockIdx.x * 256 + threadIdx.x;
    if (i < n) p[i] = 0.0f;
}

// Precompute ||c||^2 for all 512 codes into workspace.
__global__ __launch_bounds__(256) void cbnorm_kernel(const float* __restrict__ cb,
                                                     float* __restrict__ cn) {
    int k = blockIdx.x * 256 + threadIdx.x;
    if (k >= NCODES) return;
    const float4* c4 = (const float4*)(cb + (size_t)k * CDIM);
    float s = 0.0f;
    #pragma unroll
    for (int q = 0; q < 16; ++q) {
        float4 c = c4[q];
        s = fmaf(c.x, c.x, s);
        s = fmaf(c.y, c.y, s);
        s = fmaf(c.z, c.z, s);
        s = fmaf(c.w, c.w, s);
    }
    cn[k] = s;
}

// One block per (b, c) row. Radix-2 Stockham FFT (LDS ping-pong), Hilbert
// multiplier h[k]/N, inverse FFT, atan2 -> atomic mean over channels.
// 512 threads: 8 waves/block, 2 blocks/CU (80KB LDS) for latency hiding.
#define HT 512
__global__ __launch_bounds__(HT) void hilbert_phase_kernel(
    const float* __restrict__ x, float* __restrict__ phases) {
    __shared__ float2 bufA[TN];     // 32 KB
    __shared__ float2 bufB[TN];     // 32 KB
    __shared__ float2 tw[HN];       // 16 KB: tw[i] = exp(-2*pi*i*i_unit/4096)
    const int tid = threadIdx.x;
    const int row = blockIdx.x;         // b*9 + c
    const int b = row / NCH;
    const float* xr = x + (size_t)row * TN;

    for (int i = tid; i < HN; i += HT) {
        float ang = -3.14159265358979323846f * ((float)i / (float)HN);
        float s, c;
        sincosf(ang, &s, &c);
        tw[i] = make_float2(c, s);
    }
    for (int i = tid; i < TN; i += HT) {
        bufA[i] = make_float2(xr[i], 0.0f);
    }
    __syncthreads();

    float2* src = bufA;
    float2* dst = bufB;
    // ---- forward FFT (12 stages) ----
    for (int stage = 0; stage < 12; ++stage) {
        const int m = 1 << stage;
        for (int idx = tid; idx < HN; idx += HT) {
            const int kk = idx & (m - 1);
            const int jm = idx - kk;               // j*m
            float2 a = src[idx];
            float2 bb = src[idx + HN];
            float2 w = tw[jm];
            float2 sum = make_float2(a.x + bb.x, a.y + bb.y);
            float2 dif = make_float2(a.x - bb.x, a.y - bb.y);
            dst[2 * jm + kk] = sum;
            dst[2 * jm + kk + m] = cmulf(dif, w);
        }
        __syncthreads();
        float2* t0 = src; src = dst; dst = t0;
    }
    // src now holds X[k] in natural order. Apply h[k]/N.
    const float inv = 1.0f / (float)TN;
    for (int i = tid; i < TN; i += HT) {
        float sc;
        if (i == 0 || i == HN) sc = inv;
        else if (i < HN) sc = 2.0f * inv;
        else sc = 0.0f;
        float2 v = src[i];
        v.x *= sc; v.y *= sc;
        src[i] = v;
    }
    __syncthreads();
    // ---- inverse FFT (conjugate twiddles, scale already folded in) ----
    for (int stage = 0; stage < 12; ++stage) {
        const int m = 1 << stage;
        for (int idx = tid; idx < HN; idx += HT) {
            const int kk = idx & (m - 1);
            const int jm = idx - kk;
            float2 a = src[idx];
            float2 bb = src[idx + HN];
            float2 w = tw[jm];
            w.y = -w.y;
            float2 sum = make_float2(a.x + bb.x, a.y + bb.y);
            float2 dif = make_float2(a.x - bb.x, a.y - bb.y);
            dst[2 * jm + kk] = sum;
            dst[2 * jm + kk + m] = cmulf(dif, w);
        }
        __syncthreads();
        float2* t0 = src; src = dst; dst = t0;
    }
    // src holds the analytic signal. phase = atan2(im, re); mean over 9 ch.
    float* ph = phases + (size_t)b * TN;
    for (int i = tid; i < TN; i += HT) {
        float2 v = src[i];
        float p = atan2f(v.y, v.x);
        atomicAdd(&ph[i], p * (1.0f / 9.0f));
    }
}

// 512 blocks x 256 threads, 1 point/thread. Codebook rows read via
// wave-uniform addresses -> scalar loads (no LDS staging, no occupancy cap).
// score = ||c||^2 - 2 f.c (||f||^2 constant per point); first-min tie-break.
__global__ __launch_bounds__(256, 4) void vq_kernel(
    const float* __restrict__ imu,
    const float* __restrict__ Wm, const float* __restrict__ bm,
    const float* __restrict__ Wp, const float* __restrict__ bp,
    const float* __restrict__ cb,
    const float* __restrict__ cn,
    const float* __restrict__ phases,
    float* __restrict__ out_q, float* __restrict__ out_i) {
    __shared__ int s_idx[256];
    const int tid = threadIdx.x;
    const int p = blockIdx.x * 256 + tid;
    const int b = p >> 12;
    const int t = p & (TN - 1);

    // ---- features ----
    float xc[9];
    #pragma unroll
    for (int c = 0; c < 9; ++c)
        xc[c] = imu[((size_t)(b * 9 + c)) * TN + t];
    float phv = phases[p];
    float sp, cp;
    __sincosf(phv, &sp, &cp);
    // __sincosf is fast-math; match reference precision with sincosf instead:
    sincosf(phv, &sp, &cp);

    float f[CDIM];
    #pragma unroll
    for (int j = 0; j < 32; ++j) {
        float a = bm[j];
        #pragma unroll
        for (int c = 0; c < 9; ++c) a = fmaf(Wm[j * 9 + c], xc[c], a);
        f[j] = a;
    }
    #pragma unroll
    for (int j = 0; j < 32; ++j) {
        float a = bp[j];
        #pragma unroll
        for (int c = 0; c < 7; ++c) a = fmaf(Wp[j * 9 + c], xc[c], a);
        a = fmaf(Wp[j * 9 + 7], cp, a);
        a = fmaf(Wp[j * 9 + 8], sp, a);
        f[32 + j] = a;
    }

    // ---- argmin over 512 codes; codebook rows are wave-uniform ----
    float best = 3.4e38f;
    int bi = 0;
    for (int k = 0; k < NCODES; ++k) {
        const float* crow = cb + (size_t)k * CDIM;
        float a0 = 0.0f, a1 = 0.0f, a2 = 0.0f, a3 = 0.0f;
        #pragma unroll
        for (int d = 0; d < CDIM; d += 4) {
            a0 = fmaf(f[d + 0], crow[d + 0], a0);
            a1 = fmaf(f[d + 1], crow[d + 1], a1);
            a2 = fmaf(f[d + 2], crow[d + 2], a2);
            a3 = fmaf(f[d + 3], crow[d + 3], a3);
        }
        const float acc = (a0 + a1) + (a2 + a3);
        const float s = fmaf(-2.0f, acc, cn[k]);
        if (s < best) { best = s; bi = k; }
    }

    out_i[p] = (float)bi;
    s_idx[tid] = bi;
    __syncthreads();

    // ---- cooperative coalesced gather of quantized rows from global cb ----
    const int p0 = blockIdx.x * 256;
    float4* oq = (float4*)out_q;
    const float4* c4g = (const float4*)cb;
    for (int i = tid; i < 256 * 16; i += 256) {
        const int pt = i >> 4;
        const int q = i & 15;
        oq[(size_t)(p0 + pt) * 16 + q] = c4g[(size_t)s_idx[pt] * 16 + q];
    }
}

extern "C" void kernel_launch(void* const* d_in, const int* in_sizes, int n_in,
                              void* d_out, int out_size, void* d_ws, size_t ws_size,
                              hipStream_t stream) {
    const float* imu = (const float*)d_in[0];
    const float* Wm  = (const float*)d_in[1];
    const float* bm  = (const float*)d_in[2];
    const float* Wp  = (const float*)d_in[3];
    const float* bp  = (const float*)d_in[4];
    const float* cb  = (const float*)d_in[5];

    float* out_q = (float*)d_out;                          // (32,4096,64)
    float* out_i = out_q + (size_t)NB * TN * CDIM;         // (32,4096) as float
    float* out_p = out_i + (size_t)NB * TN;                // (32,4096) phases
    float* cn    = (float*)d_ws;                           // 512 floats

    zero_kernel<<<(NB * TN + 255) / 256, 256, 0, stream>>>(out_p, NB * TN);
    cbnorm_kernel<<<(NCODES + 255) / 256, 256, 0, stream>>>(cb, cn);
    hilbert_phase_kernel<<<NB * NCH, HT, 0, stream>>>(imu, out_p);
    vq_kernel<<<(NB * TN) / 256, 256, 0, stream>>>(imu, Wm, bm, Wp, bp, cb,
                                                   cn, out_p, out_q, out_i);
}

// Round 3
// 277.633 us; speedup vs baseline: 1.1519x; 1.1519x over previous
//
#include <hip/hip_runtime.h>
#include <math.h>

#define TN 4096
#define HN 2048
#define NB 32
#define NCH 9
#define NCODES 512
#define CDIM 64
#define CHUNK 128

__device__ __forceinline__ float2 cmulf(float2 a, float2 b) {
    return make_float2(a.x * b.x - a.y * b.y, a.x * b.y + a.y * b.x);
}
__device__ __forceinline__ float2 f2add(float2 a, float2 b) {
    return make_float2(a.x + b.x, a.y + b.y);
}
__device__ __forceinline__ float2 f2sub(float2 a, float2 b) {
    return make_float2(a.x - b.x, a.y - b.y);
}

__global__ __launch_bounds__(256) void zero_kernel(float* __restrict__ p, int n) {
    int i = blockIdx.x * 256 + threadIdx.x;
    if (i < n) p[i] = 0.0f;
}

// Precompute ||c||^2 for all 512 codes into workspace.
__global__ __launch_bounds__(256) void cbnorm_kernel(const float* __restrict__ cb,
                                                     float* __restrict__ cn) {
    int k = blockIdx.x * 256 + threadIdx.x;
    if (k >= NCODES) return;
    const float4* c4 = (const float4*)(cb + (size_t)k * CDIM);
    float s = 0.0f;
    #pragma unroll
    for (int q = 0; q < 16; ++q) {
        float4 c = c4[q];
        s = fmaf(c.x, c.x, s);
        s = fmaf(c.y, c.y, s);
        s = fmaf(c.z, c.z, s);
        s = fmaf(c.w, c.w, s);
    }
    cn[k] = s;
}

// One block per (b, c) row. Radix-4 Stockham FFT (LDS ping-pong), 6 fwd +
// 6 inv stages, Hilbert multiplier h[k]/N, atan2 -> atomic mean over channels.
#define HT 512
__global__ __launch_bounds__(HT) void hilbert_phase_kernel(
    const float* __restrict__ x, float* __restrict__ phases) {
    __shared__ float2 bufA[TN];     // 32 KB
    __shared__ float2 bufB[TN];     // 32 KB
    __shared__ float2 tw[HN];       // 16 KB: tw[i] = exp(-2*pi*i/4096 * i)
    const int tid = threadIdx.x;
    const int row = blockIdx.x;         // b*9 + c
    const int b = row / NCH;
    const float* xr = x + (size_t)row * TN;

    for (int i = tid; i < HN; i += HT) {
        float ang = -3.14159265358979323846f * ((float)i / (float)HN);
        float s, c;
        sincosf(ang, &s, &c);
        tw[i] = make_float2(c, s);
    }
    for (int i = tid; i < TN; i += HT) {
        bufA[i] = make_float2(xr[i], 0.0f);
    }
    __syncthreads();

    float2* src = bufA;
    float2* dst = bufB;
    // ---- forward FFT: 6 radix-4 DIF Stockham stages ----
    for (int stage = 0; stage < 6; ++stage) {
        const int m = 1 << (2 * stage);
        for (int idx = tid; idx < 1024; idx += HT) {
            const int kk = idx & (m - 1);
            const int jm = idx - kk;               // j*m
            float2 a0 = src[idx];
            float2 a1 = src[idx + 1024];
            float2 a2 = src[idx + 2048];
            float2 a3 = src[idx + 3072];
            float2 b0 = f2add(a0, a2);
            float2 b1 = f2add(a1, a3);
            float2 b2 = f2sub(a0, a2);
            float2 b3 = f2sub(a1, a3);
            float2 w1 = tw[jm];
            float2 w2 = tw[2 * jm];
            float2 w3 = cmulf(w1, w2);
            // y0 = b0+b1; y1 = (b2 - i b3) w1; y2 = (b0-b1) w2; y3 = (b2 + i b3) w3
            float2 y0 = f2add(b0, b1);
            float2 mi = make_float2(b2.x + b3.y, b2.y - b3.x);  // b2 - i*b3
            float2 pi_ = make_float2(b2.x - b3.y, b2.y + b3.x); // b2 + i*b3
            dst[4 * jm + kk]         = y0;
            dst[4 * jm + kk + m]     = cmulf(mi, w1);
            dst[4 * jm + kk + 2 * m] = cmulf(f2sub(b0, b1), w2);
            dst[4 * jm + kk + 3 * m] = cmulf(pi_, w3);
        }
        __syncthreads();
        float2* t0 = src; src = dst; dst = t0;
    }
    // src holds X[k] natural order. Apply h[k]/N.
    const float inv = 1.0f / (float)TN;
    for (int i = tid; i < TN; i += HT) {
        float sc;
        if (i == 0 || i == HN) sc = inv;
        else if (i < HN) sc = 2.0f * inv;
        else sc = 0.0f;
        float2 v = src[i];
        v.x *= sc; v.y *= sc;
        src[i] = v;
    }
    __syncthreads();
    // ---- inverse FFT: conjugate twiddles, i -> -i ----
    for (int stage = 0; stage < 6; ++stage) {
        const int m = 1 << (2 * stage);
        for (int idx = tid; idx < 1024; idx += HT) {
            const int kk = idx & (m - 1);
            const int jm = idx - kk;
            float2 a0 = src[idx];
            float2 a1 = src[idx + 1024];
            float2 a2 = src[idx + 2048];
            float2 a3 = src[idx + 3072];
            float2 b0 = f2add(a0, a2);
            float2 b1 = f2add(a1, a3);
            float2 b2 = f2sub(a0, a2);
            float2 b3 = f2sub(a1, a3);
            float2 w1 = tw[jm];      w1.y = -w1.y;
            float2 w2 = tw[2 * jm];  w2.y = -w2.y;
            float2 w3 = cmulf(w1, w2);
            float2 y0 = f2add(b0, b1);
            float2 pi_ = make_float2(b2.x - b3.y, b2.y + b3.x); // b2 + i*b3
            float2 mi = make_float2(b2.x + b3.y, b2.y - b3.x);  // b2 - i*b3
            dst[4 * jm + kk]         = y0;
            dst[4 * jm + kk + m]     = cmulf(pi_, w1);
            dst[4 * jm + kk + 2 * m] = cmulf(f2sub(b0, b1), w2);
            dst[4 * jm + kk + 3 * m] = cmulf(mi, w3);
        }
        __syncthreads();
        float2* t0 = src; src = dst; dst = t0;
    }
    // src holds the analytic signal. phase = atan2(im, re); mean over 9 ch.
    float* ph = phases + (size_t)b * TN;
    for (int i = tid; i < TN; i += HT) {
        float2 v = src[i];
        float p = atan2f(v.y, v.x);
        atomicAdd(&ph[i], p * (1.0f / 9.0f));
    }
}

// 256 blocks x 256 threads, 2 points/thread, codebook chunked in LDS
// (128 codes = 32 KB). launch_bounds(256,3): 170-VGPR budget so f0/f1 stay
// in registers (round-2 spill fix). Broadcast ds_read_b128 per code row.
__global__ __launch_bounds__(256, 3) void vq_kernel(
    const float* __restrict__ imu,
    const float* __restrict__ Wm, const float* __restrict__ bm,
    const float* __restrict__ Wp, const float* __restrict__ bp,
    const float* __restrict__ cb,
    const float* __restrict__ cn,
    const float* __restrict__ phases,
    float* __restrict__ out_q, float* __restrict__ out_i) {
    __shared__ __align__(16) float s_cb[CHUNK * CDIM];   // 32 KB
    __shared__ float s_cn[NCODES];
    __shared__ int s_idx[512];
    const int tid = threadIdx.x;
    const int p0 = blockIdx.x * 512;

    for (int i = tid; i < NCODES; i += 256) s_cn[i] = cn[i];

    // ---- features for 2 points ----
    float f0[CDIM], f1[CDIM];
    #pragma unroll
    for (int pp = 0; pp < 2; ++pp) {
        const int p = p0 + pp * 256 + tid;
        float* f = pp ? f1 : f0;
        const int b = p >> 12;
        const int t = p & (TN - 1);
        float xc[9];
        #pragma unroll
        for (int c = 0; c < 9; ++c)
            xc[c] = imu[((size_t)(b * 9 + c)) * TN + t];
        float phv = phases[p];
        float sp, cp;
        sincosf(phv, &sp, &cp);
        #pragma unroll
        for (int j = 0; j < 32; ++j) {
            float a = bm[j];
            #pragma unroll
            for (int c = 0; c < 9; ++c) a = fmaf(Wm[j * 9 + c], xc[c], a);
            f[j] = a;
        }
        #pragma unroll
        for (int j = 0; j < 32; ++j) {
            float a = bp[j];
            #pragma unroll
            for (int c = 0; c < 7; ++c) a = fmaf(Wp[j * 9 + c], xc[c], a);
            a = fmaf(Wp[j * 9 + 7], cp, a);
            a = fmaf(Wp[j * 9 + 8], sp, a);
            f[32 + j] = a;
        }
    }

    // ---- argmin over 4 chunks of 128 codes ----
    float best0 = 3.4e38f, best1 = 3.4e38f;
    int bi0 = 0, bi1 = 0;
    for (int ch = 0; ch < 4; ++ch) {
        __syncthreads();
        const float4* src4 = (const float4*)(cb + (size_t)ch * CHUNK * CDIM);
        #pragma unroll
        for (int i = 0; i < 8; ++i)
            ((float4*)s_cb)[tid + 256 * i] = src4[tid + 256 * i];
        __syncthreads();
        const int kbase = ch * CHUNK;
        for (int k = 0; k < CHUNK; ++k) {
            const float4* c4 = (const float4*)(s_cb + k * CDIM);
            float a00 = 0.0f, a01 = 0.0f, a10 = 0.0f, a11 = 0.0f;
            #pragma unroll
            for (int q = 0; q < 16; q += 2) {
                float4 ca = c4[q];
                float4 cc = c4[q + 1];
                a00 = fmaf(f0[4 * q + 0], ca.x, a00);
                a00 = fmaf(f0[4 * q + 1], ca.y, a00);
                a00 = fmaf(f0[4 * q + 2], ca.z, a00);
                a00 = fmaf(f0[4 * q + 3], ca.w, a00);
                a01 = fmaf(f0[4 * q + 4], cc.x, a01);
                a01 = fmaf(f0[4 * q + 5], cc.y, a01);
                a01 = fmaf(f0[4 * q + 6], cc.z, a01);
                a01 = fmaf(f0[4 * q + 7], cc.w, a01);
                a10 = fmaf(f1[4 * q + 0], ca.x, a10);
                a10 = fmaf(f1[4 * q + 1], ca.y, a10);
                a10 = fmaf(f1[4 * q + 2], ca.z, a10);
                a10 = fmaf(f1[4 * q + 3], ca.w, a10);
                a11 = fmaf(f1[4 * q + 4], cc.x, a11);
                a11 = fmaf(f1[4 * q + 5], cc.y, a11);
                a11 = fmaf(f1[4 * q + 6], cc.z, a11);
                a11 = fmaf(f1[4 * q + 7], cc.w, a11);
            }
            const float cnk = s_cn[kbase + k];
            const float s0 = fmaf(-2.0f, a00 + a01, cnk);
            const float s1 = fmaf(-2.0f, a10 + a11, cnk);
            if (s0 < best0) { best0 = s0; bi0 = kbase + k; }
            if (s1 < best1) { best1 = s1; bi1 = kbase + k; }
        }
    }

    out_i[p0 + tid] = (float)bi0;
    out_i[p0 + 256 + tid] = (float)bi1;
    s_idx[tid] = bi0;
    s_idx[256 + tid] = bi1;
    __syncthreads();

    // ---- cooperative coalesced gather of quantized rows from global cb ----
    float4* oq = (float4*)out_q;
    const float4* c4g = (const float4*)cb;
    for (int i = tid; i < 512 * 16; i += 256) {
        const int pt = i >> 4;
        const int q = i & 15;
        oq[(size_t)(p0 + pt) * 16 + q] = c4g[(size_t)s_idx[pt] * 16 + q];
    }
}

extern "C" void kernel_launch(void* const* d_in, const int* in_sizes, int n_in,
                              void* d_out, int out_size, void* d_ws, size_t ws_size,
                              hipStream_t stream) {
    const float* imu = (const float*)d_in[0];
    const float* Wm  = (const float*)d_in[1];
    const float* bm  = (const float*)d_in[2];
    const float* Wp  = (const float*)d_in[3];
    const float* bp  = (const float*)d_in[4];
    const float* cb  = (const float*)d_in[5];

    float* out_q = (float*)d_out;                          // (32,4096,64)
    float* out_i = out_q + (size_t)NB * TN * CDIM;         // (32,4096) as float
    float* out_p = out_i + (size_t)NB * TN;                // (32,4096) phases
    float* cn    = (float*)d_ws;                           // 512 floats

    zero_kernel<<<(NB * TN + 255) / 256, 256, 0, stream>>>(out_p, NB * TN);
    cbnorm_kernel<<<(NCODES + 255) / 256, 256, 0, stream>>>(cb, cn);
    hilbert_phase_kernel<<<NB * NCH, HT, 0, stream>>>(imu, out_p);
    vq_kernel<<<(NB * TN) / 512, 256, 0, stream>>>(imu, Wm, bm, Wp, bp, cb,
                                                   cn, out_p, out_q, out_i);
}

// Round 4
// 235.978 us; speedup vs baseline: 1.3552x; 1.1765x over previous
//
#include <hip/hip_runtime.h>
#include <math.h>

#define TN 4096
#define HN 2048
#define NB 32
#define NCH 9
#define NCODES 512
#define CDIM 64

__device__ __forceinline__ float2 cmulf(float2 a, float2 b) {
    return make_float2(a.x * b.x - a.y * b.y, a.x * b.y + a.y * b.x);
}
__device__ __forceinline__ float2 f2add(float2 a, float2 b) {
    return make_float2(a.x + b.x, a.y + b.y);
}
__device__ __forceinline__ float2 f2sub(float2 a, float2 b) {
    return make_float2(a.x - b.x, a.y - b.y);
}

// blocks 0..511: zero phases (32*4096). block 512: codebook norms.
__global__ __launch_bounds__(256) void prep_kernel(const float* __restrict__ cb,
                                                   float* __restrict__ cn,
                                                   float* __restrict__ ph) {
    const int bid = blockIdx.x;
    const int tid = threadIdx.x;
    if (bid < 512) {
        ph[bid * 256 + tid] = 0.0f;
        return;
    }
    for (int k = tid; k < NCODES; k += 256) {
        const float4* c4 = (const float4*)(cb + (size_t)k * CDIM);
        float s = 0.0f;
        #pragma unroll
        for (int q = 0; q < 16; ++q) {
            float4 c = c4[q];
            s = fmaf(c.x, c.x, s);
            s = fmaf(c.y, c.y, s);
            s = fmaf(c.z, c.z, s);
            s = fmaf(c.w, c.w, s);
        }
        cn[k] = s;
    }
}

// Paired-row Hilbert: one complex FFT serves TWO real rows.
// z = x1 + i*x2; d = ifft(h * fft(z)) = a1 + i*a2 with re(a1)=x1, re(a2)=x2:
//   H1 = im(d) - x2, H2 = x1 - re(d); phase_i = atan2(H_i, x_i).
// Radix-4 Stockham body identical to the round-3-validated kernel.
#define HT 512
__global__ __launch_bounds__(HT) void hilbert_phase_kernel(
    const float* __restrict__ x, float* __restrict__ phases) {
    __shared__ float2 bufA[TN];     // 32 KB
    __shared__ float2 bufB[TN];     // 32 KB
    __shared__ float2 tw[HN];       // 16 KB
    const int tid = threadIdx.x;
    const int row1 = 2 * blockIdx.x;        // global row in [0, 288)
    const int row2 = row1 + 1;
    const int b1 = row1 / NCH;
    const int b2 = row2 / NCH;
    const float* xr1 = x + (size_t)row1 * TN;
    const float* xr2 = x + (size_t)row2 * TN;

    for (int i = tid; i < HN; i += HT) {
        float ang = -3.14159265358979323846f * ((float)i / (float)HN);
        float s, c;
        sincosf(ang, &s, &c);
        tw[i] = make_float2(c, s);
    }
    for (int i = tid; i < TN; i += HT) {
        bufA[i] = make_float2(xr1[i], xr2[i]);
    }
    __syncthreads();

    float2* src = bufA;
    float2* dst = bufB;
    // ---- forward FFT: 6 radix-4 DIF Stockham stages ----
    for (int stage = 0; stage < 6; ++stage) {
        const int m = 1 << (2 * stage);
        for (int idx = tid; idx < 1024; idx += HT) {
            const int kk = idx & (m - 1);
            const int jm = idx - kk;
            float2 a0 = src[idx];
            float2 a1 = src[idx + 1024];
            float2 a2 = src[idx + 2048];
            float2 a3 = src[idx + 3072];
            float2 b0 = f2add(a0, a2);
            float2 b1 = f2add(a1, a3);
            float2 b2 = f2sub(a0, a2);
            float2 b3 = f2sub(a1, a3);
            float2 w1 = tw[jm];
            float2 w2 = tw[2 * jm];
            float2 w3 = cmulf(w1, w2);
            float2 y0 = f2add(b0, b1);
            float2 mi = make_float2(b2.x + b3.y, b2.y - b3.x);  // b2 - i*b3
            float2 pi_ = make_float2(b2.x - b3.y, b2.y + b3.x); // b2 + i*b3
            dst[4 * jm + kk]         = y0;
            dst[4 * jm + kk + m]     = cmulf(mi, w1);
            dst[4 * jm + kk + 2 * m] = cmulf(f2sub(b0, b1), w2);
            dst[4 * jm + kk + 3 * m] = cmulf(pi_, w3);
        }
        __syncthreads();
        float2* t0 = src; src = dst; dst = t0;
    }
    // h[k]/N mask
    const float inv = 1.0f / (float)TN;
    for (int i = tid; i < TN; i += HT) {
        float sc;
        if (i == 0 || i == HN) sc = inv;
        else if (i < HN) sc = 2.0f * inv;
        else sc = 0.0f;
        float2 v = src[i];
        v.x *= sc; v.y *= sc;
        src[i] = v;
    }
    __syncthreads();
    // ---- inverse FFT ----
    for (int stage = 0; stage < 6; ++stage) {
        const int m = 1 << (2 * stage);
        for (int idx = tid; idx < 1024; idx += HT) {
            const int kk = idx & (m - 1);
            const int jm = idx - kk;
            float2 a0 = src[idx];
            float2 a1 = src[idx + 1024];
            float2 a2 = src[idx + 2048];
            float2 a3 = src[idx + 3072];
            float2 b0 = f2add(a0, a2);
            float2 b1 = f2add(a1, a3);
            float2 b2 = f2sub(a0, a2);
            float2 b3 = f2sub(a1, a3);
            float2 w1 = tw[jm];      w1.y = -w1.y;
            float2 w2 = tw[2 * jm];  w2.y = -w2.y;
            float2 w3 = cmulf(w1, w2);
            float2 y0 = f2add(b0, b1);
            float2 pi_ = make_float2(b2.x - b3.y, b2.y + b3.x); // b2 + i*b3
            float2 mi = make_float2(b2.x + b3.y, b2.y - b3.x);  // b2 - i*b3
            dst[4 * jm + kk]         = y0;
            dst[4 * jm + kk + m]     = cmulf(pi_, w1);
            dst[4 * jm + kk + 2 * m] = cmulf(f2sub(b0, b1), w2);
            dst[4 * jm + kk + 3 * m] = cmulf(mi, w3);
        }
        __syncthreads();
        float2* t0 = src; src = dst; dst = t0;
    }
    // unpack both channels, atomic mean over 9 channels
    float* ph1 = phases + (size_t)b1 * TN;
    float* ph2 = phases + (size_t)b2 * TN;
    for (int i = tid; i < TN; i += HT) {
        float2 d = src[i];
        float x1v = xr1[i];
        float x2v = xr2[i];
        float H1 = d.y - x2v;
        float H2 = x1v - d.x;
        atomicAdd(&ph1[i], atan2f(H1, x1v) * (1.0f / 9.0f));
        atomicAdd(&ph2[i], atan2f(H2, x2v) * (1.0f / 9.0f));
    }
}

// vq: 2048 blocks x 256 threads. Block covers 64 points; 4 waves split the
// 512 codes (128 each). lane = point (one f[64] in regs, no pointer select);
// code-row addresses are wave-uniform -> scalar/broadcast loads, no LDS in
// the k-loop. Cross-wave argmin via packed u64 min (first-min tie-break).
__global__ __launch_bounds__(256, 4) void vq_kernel(
    const float* __restrict__ imu,
    const float* __restrict__ Wm, const float* __restrict__ bm,
    const float* __restrict__ Wp, const float* __restrict__ bp,
    const float* __restrict__ cb,
    const float* __restrict__ cn,
    const float* __restrict__ phases,
    float* __restrict__ out_q, float* __restrict__ out_i) {
    __shared__ unsigned long long s_best[4][64];
    __shared__ int s_idx[64];
    const int tid = threadIdx.x;
    const int w = tid >> 6;
    const int lane = tid & 63;
    const int p0 = blockIdx.x * 64;
    const int p = p0 + lane;
    const int b = p >> 12;
    const int t = p & (TN - 1);

    // ---- features (duplicated per wave; ~4 us total) ----
    float xc[9];
    #pragma unroll
    for (int c = 0; c < 9; ++c)
        xc[c] = imu[((size_t)(b * 9 + c)) * TN + t];
    float sp, cp;
    sincosf(phases[p], &sp, &cp);

    float f[CDIM];
    #pragma unroll
    for (int j = 0; j < 32; ++j) {
        float a = bm[j];
        #pragma unroll
        for (int c = 0; c < 9; ++c) a = fmaf(Wm[j * 9 + c], xc[c], a);
        f[j] = a;
    }
    #pragma unroll
    for (int j = 0; j < 32; ++j) {
        float a = bp[j];
        #pragma unroll
        for (int c = 0; c < 7; ++c) a = fmaf(Wp[j * 9 + c], xc[c], a);
        a = fmaf(Wp[j * 9 + 7], cp, a);
        a = fmaf(Wp[j * 9 + 8], sp, a);
        f[32 + j] = a;
    }

    // ---- this wave's 128 codes; wave-uniform row addresses ----
    const int kbase = __builtin_amdgcn_readfirstlane(w * 128);
    float best = 3.4e38f;
    int bi = 0;
    for (int k = 0; k < 128; ++k) {
        const float* crow = cb + (size_t)(kbase + k) * CDIM;
        float a0 = 0.0f, a1 = 0.0f, a2 = 0.0f, a3 = 0.0f;
        #pragma unroll
        for (int d = 0; d < CDIM; d += 4) {
            a0 = fmaf(f[d + 0], crow[d + 0], a0);
            a1 = fmaf(f[d + 1], crow[d + 1], a1);
            a2 = fmaf(f[d + 2], crow[d + 2], a2);
            a3 = fmaf(f[d + 3], crow[d + 3], a3);
        }
        const float s = fmaf(-2.0f, (a0 + a1) + (a2 + a3), cn[kbase + k]);
        if (s < best) { best = s; bi = kbase + k; }
    }

    // ---- order-preserving pack + cross-wave min ----
    unsigned ub = __float_as_uint(best);
    ub = (ub & 0x80000000u) ? ~ub : (ub | 0x80000000u);
    s_best[w][lane] = ((unsigned long long)ub << 32) | (unsigned)bi;
    __syncthreads();
    if (w == 0) {
        unsigned long long m0 = s_best[0][lane];
        unsigned long long m1 = s_best[1][lane];
        unsigned long long m2 = s_best[2][lane];
        unsigned long long m3 = s_best[3][lane];
        unsigned long long m = m0 < m1 ? m0 : m1;
        unsigned long long n = m2 < m3 ? m2 : m3;
        m = m < n ? m : n;
        const int fbi = (int)(m & 0xFFFFFFFFu);
        s_idx[lane] = fbi;
        out_i[p] = (float)fbi;
    }
    __syncthreads();

    // ---- cooperative coalesced gather of quantized rows (L2-hot cb) ----
    float4* oq = (float4*)out_q;
    const float4* c4g = (const float4*)cb;
    for (int i = tid; i < 64 * 16; i += 256) {
        const int pt = i >> 4;
        const int q = i & 15;
        oq[(size_t)(p0 + pt) * 16 + q] = c4g[(size_t)s_idx[pt] * 16 + q];
    }
}

extern "C" void kernel_launch(void* const* d_in, const int* in_sizes, int n_in,
                              void* d_out, int out_size, void* d_ws, size_t ws_size,
                              hipStream_t stream) {
    const float* imu = (const float*)d_in[0];
    const float* Wm  = (const float*)d_in[1];
    const float* bm  = (const float*)d_in[2];
    const float* Wp  = (const float*)d_in[3];
    const float* bp  = (const float*)d_in[4];
    const float* cb  = (const float*)d_in[5];

    float* out_q = (float*)d_out;                          // (32,4096,64)
    float* out_i = out_q + (size_t)NB * TN * CDIM;         // (32,4096) as float
    float* out_p = out_i + (size_t)NB * TN;                // (32,4096) phases
    float* cn    = (float*)d_ws;                           // 512 floats

    prep_kernel<<<513, 256, 0, stream>>>(cb, cn, out_p);
    hilbert_phase_kernel<<<NB * NCH / 2, HT, 0, stream>>>(imu, out_p);
    vq_kernel<<<(NB * TN) / 64, 256, 0, stream>>>(imu, Wm, bm, Wp, bp, cb,
                                                  cn, out_p, out_q, out_i);
}